// Round 6
// baseline (114.094 us; speedup 1.0000x reference)
//
#include <hip/hip_runtime.h>
#include <hip/hip_bf16.h>

// (B,T,E,H) = (4, 2048, 1024, 64); scale = E^-0.5 = 1/32.
// Ground truth: inputs fp32, output fp32. ws >= 268 MB.
// dur_us model: ~87 us fixed poison fills (2 x ~43.5 us, immovable) + ~19 us
// controllable (prep_w ~3, qkv ~6-7, attn ~5-6, gaps).
// R18 (on R17's 106.15):
//  qkv: X-LDS ELIMINATED — A-fragments lane-addressable direct from global
//   (4 waves sharing rowh re-read 16KB/step: L1-resident). Double-reg A
//   prefetch (xA/xB, T14 split); convert at use via v_cvt_pk_bf16_f32
//   (1 instr/pair vs 6-op f2bf bit-hack; RNE-identical). Drain is counted
//   vmcnt(8): 6 W-DMAs are oldest entries (in-order retire) -> barrier
//   crosses with 8 A-loads still in flight. Removes 4 ds_read_b128 +
//   2 ds_write + 12 convert-ops per thread/step from the barrier path.
//  attn: Pb conversion via cvt_pk pairs (48 -> 16 VALU per tile).
// R17-proven pieces kept: 2-phase W dbuf + one s_barrier/step, W DMA + XOR
// involution (R16 absmax-identical), 32-row frag map, epilogue, balanced attn.
constexpr int Bc = 4;
constexpr int Tc = 2048;
constexpr int Ec = 1024;
constexpr int Hc = 64;
constexpr float SCALE = 0.03125f;

typedef short  short8  __attribute__((ext_vector_type(8)));
typedef float  floatx4 __attribute__((ext_vector_type(4)));

__device__ __forceinline__ unsigned short f2bf(float f) {  // RNE
    union { float f; unsigned int i; } x;
    x.f = f;
    unsigned int r = x.i + 0x7fffu + ((x.i >> 16) & 1u);
    return (unsigned short)(r >> 16);
}

// packed fp32x2 -> bf16x2, RNE (identical to f2bf on normal values)
__device__ __forceinline__ unsigned int cvt_pk_bf16(float lo, float hi) {
    unsigned int r;
    asm volatile("v_cvt_pk_bf16_f32 %0, %1, %2" : "=v"(r) : "v"(lo), "v"(hi));
    return r;
}

// ---------------------------------------------------------------------------
// Kernel 0: W fp32 [E][H] -> Wt bf16 [H][E], x3 (r7-r12-proven). ~3 us.
// ---------------------------------------------------------------------------
__global__ __launch_bounds__(256) void prep_w(
    const float* __restrict__ Wq, const float* __restrict__ Wk,
    const float* __restrict__ Wv, unsigned short* __restrict__ Wt)
{
    const float* W = blockIdx.y == 0 ? Wq : (blockIdx.y == 1 ? Wk : Wv);
    unsigned short* D = Wt + (size_t)blockIdx.y * (Ec * Hc);
    const int i0 = blockIdx.x * 1024 + threadIdx.x * 4;
    const float4 f = *(const float4*)(W + i0);
    const float v[4] = {f.x, f.y, f.z, f.w};
    #pragma unroll
    for (int j = 0; j < 4; ++j) {
        const int i = i0 + j;            // i = e*64 + h
        D[(i & 63) * Ec + (i >> 6)] = f2bf(v[j]);
    }
}

// ---------------------------------------------------------------------------
// Kernel 1: FUSED QKV, MFMA 16x16x32 bf16, K=128 steps, 2-phase W dbuf.
// Grid 256 x 512 thr (1 block/CU, 8 waves = 2/SIMD). LDS = Ws only, 96 KB.
// Per step: issue 6 W-DMA(next) + 8 A-loads(next, regs) -> compute cur
// (12 ds_read_b128 + 16 cvt_pk + 12 MFMA/wave) -> s_waitcnt vmcnt(8)
// (drains W, leaves A in flight) -> s_barrier.
// W involution (R16-proven): store-side source chunk ^= (row&7); read-side
// colb ^= ((l16&7)<<4). Buffer safety: DMA into buf B only after the barrier
// following all reads of buf B (reads retired via MFMA lgkm waits).
// ---------------------------------------------------------------------------
__global__ __launch_bounds__(512, 2) void qkv_mfma12(
    const float* __restrict__ X, const unsigned short* __restrict__ Wt,
    unsigned short* __restrict__ Q, unsigned short* __restrict__ K,
    unsigned short* __restrict__ Vt)
{
    __shared__ __align__(16) unsigned short Ws[2][3][64][128];   // 96.0 KB

    const int tid  = threadIdx.x;
    const int wv   = tid >> 6;          // 0..7
    const int lane = tid & 63;
    const int quad = lane >> 4;
    const int l16  = lane & 15;
    const int rowh = wv >> 2;           // 0..1
    const int wq   = wv & 3;            // 0..3
    const size_t row0 = (size_t)blockIdx.x * 32;

    floatx4 acc[3];
    #pragma unroll
    for (int j = 0; j < 3; ++j)
        #pragma unroll
        for (int r = 0; r < 4; ++r) acc[j][r] = 0.f;

    // lane-private A source: row = row0 + rowh*16 + l16, col base quad*8
    const float* Xrow = X + (row0 + rowh * 16 + l16) * Ec + quad * 8;

    float4 xA[8], xB[8];

    // ---- prologue: W-DMA(t=0) then A-loads(t=0); drain W only ----
    #pragma unroll
    for (int j = 0; j < 6; ++j) {
        const int flat  = tid + 512 * j;        // 0..3071
        const int which = flat >> 10;
        const int r     = (flat >> 4) & 63;
        const int chunk = (flat & 15) ^ (r & 7);
        const unsigned short* src = Wt + which * 65536 + r * 1024 + chunk * 8;
        char* dst = (char*)&Ws[0][0][0][0] + (wv * 64 + 512 * j) * 16;
        __builtin_amdgcn_global_load_lds(
            (const __attribute__((address_space(1))) unsigned int*)src,
            (__attribute__((address_space(3))) unsigned int*)dst,
            16, 0, 0);
    }
    #pragma unroll
    for (int i = 0; i < 8; ++i)
        xA[i] = *(const float4*)(Xrow + (i >> 1) * 32 + (i & 1) * 4);
    __builtin_amdgcn_sched_barrier(0);
    asm volatile("s_waitcnt vmcnt(8)" ::: "memory");
    __builtin_amdgcn_s_barrier();

#define QKV_STEP(T, CUR, XC, XN)                                              \
    do {                                                                      \
        if ((T) < 7) {                                                        \
            const int k1 = ((T) + 1) * 128;                                   \
            _Pragma("unroll")                                                 \
            for (int j = 0; j < 6; ++j) {                                     \
                const int flat  = tid + 512 * j;                              \
                const int which = flat >> 10;                                 \
                const int r     = (flat >> 4) & 63;                           \
                const int chunk = (flat & 15) ^ (r & 7);                      \
                const unsigned short* src =                                   \
                    Wt + which * 65536 + r * 1024 + k1 + chunk * 8;           \
                char* dst = (char*)&Ws[(CUR) ^ 1][0][0][0] +                  \
                            (wv * 64 + 512 * j) * 16;                         \
                __builtin_amdgcn_global_load_lds(                             \
                    (const __attribute__((address_space(1))) unsigned int*)src,\
                    (__attribute__((address_space(3))) unsigned int*)dst,     \
                    16, 0, 0);                                                \
            }                                                                 \
            _Pragma("unroll")                                                 \
            for (int i = 0; i < 8; ++i)                                       \
                XN[i] = *(const float4*)(Xrow + k1 + (i >> 1) * 32 +          \
                                         (i & 1) * 4);                        \
        }                                                                     \
        __builtin_amdgcn_sched_barrier(0);                                    \
        _Pragma("unroll")                                                     \
        for (int ks = 0; ks < 4; ++ks) {                                      \
            union { unsigned int u[4]; short8 s8; } au;                       \
            au.u[0] = cvt_pk_bf16(XC[ks * 2].x, XC[ks * 2].y);                \
            au.u[1] = cvt_pk_bf16(XC[ks * 2].z, XC[ks * 2].w);                \
            au.u[2] = cvt_pk_bf16(XC[ks * 2 + 1].x, XC[ks * 2 + 1].y);        \
            au.u[3] = cvt_pk_bf16(XC[ks * 2 + 1].z, XC[ks * 2 + 1].w);        \
            const short8 a = au.s8;                                           \
            short8 b[3];                                                      \
            _Pragma("unroll")                                                 \
            for (int j = 0; j < 3; ++j) {                                     \
                const int f    = 3 * wq + j;                                  \
                const int row  = 16 * (f & 3) + l16;                          \
                const int colb = (ks * 64 + quad * 16) ^ ((l16 & 7) << 4);    \
                b[j] = *(const short8*)((const char*)&Ws[CUR][f >> 2][row][0] \
                                        + colb);                              \
            }                                                                 \
            _Pragma("unroll")                                                 \
            for (int j = 0; j < 3; ++j)                                       \
                acc[j] = __builtin_amdgcn_mfma_f32_16x16x32_bf16(             \
                    a, b[j], acc[j], 0, 0, 0);                                \
        }                                                                     \
        if ((T) < 7) {                                                        \
            __builtin_amdgcn_sched_barrier(0);                                \
            asm volatile("s_waitcnt vmcnt(8)" ::: "memory");                  \
            __builtin_amdgcn_s_barrier();                                     \
        }                                                                     \
    } while (0)

    for (int tt = 0; tt < 4; ++tt) {
        QKV_STEP(2 * tt,     0, xA, xB);
        QKV_STEP(2 * tt + 1, 1, xB, xA);
    }
#undef QKV_STEP

    // Epilogue. C/D: col = lane&15, row = quad*4 + reg (r7-r12-proven).
    const size_t rbase = row0 + rowh * 16;
    #pragma unroll
    for (int j = 0; j < 3; ++j) {
        const int f  = 3 * wq + j;
        const int mf = f >> 2, nf = f & 3;
        if (mf < 2) {
            unsigned short* O = mf == 0 ? Q : K;
            #pragma unroll
            for (int r = 0; r < 4; ++r) {
                float x = acc[j][r];
                if (!(x > -1.0e4f && x < 1.0e4f)) x = 11111.0f;   // diag
                O[(rbase + quad * 4 + r) * Hc + 16 * nf + l16] = f2bf(x);
            }
        } else {
            // V^T: Vt[b][h][t] (r8-proven). 16-row half shares one b.
            const size_t b  = rbase >> 11;
            const int    t0 = (int)(rbase & 2047) + quad * 4;
            unsigned short* VtB = Vt + b * ((size_t)Hc * Tc);
            unsigned int pk[2];
            #pragma unroll
            for (int half = 0; half < 2; ++half) {
                float x0 = acc[j][half * 2 + 0], x1 = acc[j][half * 2 + 1];
                if (!(x0 > -1.0e4f && x0 < 1.0e4f)) x0 = 11111.0f;
                if (!(x1 > -1.0e4f && x1 < 1.0e4f)) x1 = 11111.0f;
                pk[half] = (unsigned int)f2bf(x0) | ((unsigned int)f2bf(x1) << 16);
            }
            uint2 st; st.x = pk[0]; st.y = pk[1];
            *(uint2*)(VtB + (size_t)(16 * nf + l16) * Tc + t0) = st;
        }
    }
}

// ---------------------------------------------------------------------------
// Kernel 2: causal flash attention — r10/r11/r12-proven core + R15-verified
// polish (balanced pairing, shfl-lS, float2 accS reads, setprio).
// R18: Pb conversion via cvt_pk pairs (16 f2bf x3ops -> 8 cvt_pk + 8 shifts).
// ---------------------------------------------------------------------------
__global__ __launch_bounds__(512, 4) void attn_mfma7(
    const unsigned short* __restrict__ Q, const unsigned short* __restrict__ K,
    const unsigned short* __restrict__ Vt, float* __restrict__ Out)
{
    __shared__ __align__(16) unsigned short Pb[8][16][72];   // 18 KB
    __shared__ __align__(16) float accS[8][16][64];          // 32 KB
    __shared__ __align__(16) float lSr[8][16];               // 0.5 KB

    const int tid  = threadIdx.x;
    const int wv   = tid >> 6;            // 0..7
    const int lane = tid & 63;
    const int quad = lane >> 4;
    const int l16  = lane & 15;
    // balanced heavy/light pairing over dispatch-linear id
    const int id   = blockIdx.x + 128 * blockIdx.y;   // 0..511, dispatch order
    const int jj   = id & 255;
    const int qt   = (id < 256) ? (127 - (jj >> 2)) : (jj >> 2);
    const int b    = jj & 3;
    const int qend = qt * 16 + 16;
    const size_t base = (size_t)b * Tc * Hc;
    const unsigned short* VtB = Vt + (size_t)b * Hc * Tc;

    short8 aQ[2];
    #pragma unroll
    for (int ks = 0; ks < 2; ++ks)
        aQ[ks] = *(const short8*)(Q + base +
            (size_t)(qt * 16 + l16) * Hc + ks * 32 + quad * 8);

    floatx4 acc[4];
    float l_st[4];
    #pragma unroll
    for (int nh = 0; nh < 4; ++nh)
        #pragma unroll
        for (int r = 0; r < 4; ++r) acc[nh][r] = 0.f;
    #pragma unroll
    for (int r = 0; r < 4; ++r) l_st[r] = 0.f;

    for (int kb = wv * 64; kb < qend; kb += 512) {
        floatx4 s[4];
        #pragma unroll
        for (int ni = 0; ni < 4; ++ni)
            #pragma unroll
            for (int r = 0; r < 4; ++r) s[ni][r] = 0.f;
        #pragma unroll
        for (int ks = 0; ks < 2; ++ks) {
            short8 bk[4];
            #pragma unroll
            for (int ni = 0; ni < 4; ++ni)
                bk[ni] = *(const short8*)(K + base +
                    (size_t)(kb + 16 * ni + l16) * Hc + ks * 32 + quad * 8);
            __builtin_amdgcn_s_setprio(1);
            #pragma unroll
            for (int ni = 0; ni < 4; ++ni)
                s[ni] = __builtin_amdgcn_mfma_f32_16x16x32_bf16(aQ[ks], bk[ni], s[ni], 0, 0, 0);
            __builtin_amdgcn_s_setprio(0);
        }

        #pragma unroll
        for (int r = 0; r < 4; ++r) {
            const int qrow = qt * 16 + quad * 4 + r;
            #pragma unroll
            for (int ni = 0; ni < 4; ++ni) {
                const int kcol = kb + 16 * ni + l16;
                const float p = (kcol > qrow) ? 0.f : __expf(s[ni][r] * SCALE);
                s[ni][r] = p;
                l_st[r] += p;
            }
        }
        #pragma unroll
        for (int ni = 0; ni < 4; ++ni) {
            const unsigned int a01 = cvt_pk_bf16(s[ni][0], s[ni][1]);
            const unsigned int a23 = cvt_pk_bf16(s[ni][2], s[ni][3]);
            Pb[wv][quad * 4 + 0][16 * ni + l16] = (unsigned short)a01;
            Pb[wv][quad * 4 + 1][16 * ni + l16] = (unsigned short)(a01 >> 16);
            Pb[wv][quad * 4 + 2][16 * ni + l16] = (unsigned short)a23;
            Pb[wv][quad * 4 + 3][16 * ni + l16] = (unsigned short)(a23 >> 16);
        }

        #pragma unroll
        for (int ks = 0; ks < 2; ++ks) {
            const short8 aP = *(const short8*)&Pb[wv][l16][ks * 32 + quad * 8];
            short8 bv[4];
            #pragma unroll
            for (int nh = 0; nh < 4; ++nh)
                bv[nh] = *(const short8*)(VtB +
                    (size_t)(16 * nh + l16) * Tc + kb + ks * 32 + quad * 8);
            __builtin_amdgcn_s_setprio(1);
            #pragma unroll
            for (int nh = 0; nh < 4; ++nh)
                acc[nh] = __builtin_amdgcn_mfma_f32_16x16x32_bf16(aP, bv[nh], acc[nh], 0, 0, 0);
            __builtin_amdgcn_s_setprio(0);
        }
    }

    #pragma unroll
    for (int nh = 0; nh < 4; ++nh)
        #pragma unroll
        for (int r = 0; r < 4; ++r)
            accS[wv][quad * 4 + r][16 * nh + l16] = acc[nh][r];
    // reduce l_st across the 16 lanes of each quad (xor masks 1,2,4,8 stay
    // within the 16-lane group), then one scalar per (wave, q-row)
    #pragma unroll
    for (int r = 0; r < 4; ++r) {
        float v = l_st[r];
        v += __shfl_xor(v, 1);
        v += __shfl_xor(v, 2);
        v += __shfl_xor(v, 4);
        v += __shfl_xor(v, 8);
        l_st[r] = v;
    }
    if (l16 == 0)
        #pragma unroll
        for (int r = 0; r < 4; ++r)
            lSr[wv][quad * 4 + r] = l_st[r];
    __syncthreads();

    {
        const int q  = tid >> 5;              // 0..15
        const int h0 = (tid & 31) * 2;        // 0..62
        float denom = 0.f;
        #pragma unroll
        for (int w = 0; w < 8; ++w)
            denom += lSr[w][q];
        const float inv = 1.f / denom;
        float o0 = 0.f, o1 = 0.f;
        #pragma unroll
        for (int w = 0; w < 8; ++w) {
            const float2 v = *(const float2*)&accS[w][q][h0];
            o0 += v.x; o1 += v.y;
        }
        o0 *= inv; o1 *= inv;
        if (!(o0 > -1.0e5f && o0 < 1.0e5f)) o0 = 555.0f;   // diag
        if (!(o1 > -1.0e5f && o1 < 1.0e5f)) o1 = 555.0f;
        float2 st; st.x = o0; st.y = o1;
        *(float2*)(Out + base + (size_t)(qt * 16 + q) * Hc + h0) = st;
    }
}

extern "C" void kernel_launch(void* const* d_in, const int* in_sizes, int n_in,
                              void* d_out, int out_size, void* d_ws, size_t ws_size,
                              hipStream_t stream)
{
    const float* X  = (const float*)d_in[0];
    const float* Wq = (const float*)d_in[1];
    const float* Wk = (const float*)d_in[2];
    const float* Wv = (const float*)d_in[3];

    const size_t N = (size_t)Bc * Tc * Hc;          // 524,288
    unsigned short* Wt  = (unsigned short*)d_ws;    // 384 KB bf16 W^T x3
    unsigned short* Qws = Wt + 3 * (size_t)Ec * Hc; // 1 MB
    unsigned short* Kws = Qws + N;                  // 1 MB
    unsigned short* Vtw = Kws + N;                  // 1 MB (V^T [b][h][t])

    prep_w<<<dim3(64, 3), dim3(256), 0, stream>>>(Wq, Wk, Wv, Wt);
    qkv_mfma12<<<dim3(256), dim3(512), 0, stream>>>(X, Wt, Qws, Kws, Vtw);
    attn_mfma7<<<dim3(128, 4), dim3(512), 0, stream>>>(
        Qws, Kws, Vtw, (float*)d_out);
}

// Round 7
// 105.776 us; speedup vs baseline: 1.0786x; 1.0786x over previous
//
#include <hip/hip_runtime.h>
#include <hip/hip_bf16.h>

// (B,T,E,H) = (4, 2048, 1024, 64); scale = E^-0.5 = 1/32.
// Ground truth: inputs fp32, output fp32. ws >= 268 MB.
// dur_us model: ~87 us fixed poison fills (2 x ~43.5 us, immovable) + ~19 us
// controllable (prep_w, qkv, attn, gaps).
// R19: REVERT qkv+attn to R17 exactly (106.15-proven champion). R18's
// X-from-global qkv (+cvt_pk attn) regressed +8 us — scattered A-loads
// (32 lines/load, x4 wave redundancy) + asm-volatile-pinned cvt chains;
// reverted, do not retry without isolation.
// NEW (isolated): prep_w2 — LDS-staged 64x64 tile transpose. Old prep_w did
// 196K scattered 2B stores (8KB thread stride, ~10x store penalty, ~3 us for
// 1.9 MB). New: coalesced float4 loads -> pad-68 LDS -> 32B/thread contiguous
// stores. Same f2bf RNE -> Wt bit-identical -> absmax unchanged.
constexpr int Bc = 4;
constexpr int Tc = 2048;
constexpr int Ec = 1024;
constexpr int Hc = 64;
constexpr float SCALE = 0.03125f;

typedef short  short8  __attribute__((ext_vector_type(8)));
typedef float  floatx4 __attribute__((ext_vector_type(4)));

__device__ __forceinline__ unsigned short f2bf(float f) {  // RNE
    union { float f; unsigned int i; } x;
    x.f = f;
    unsigned int r = x.i + 0x7fffu + ((x.i >> 16) & 1u);
    return (unsigned short)(r >> 16);
}

// ---------------------------------------------------------------------------
// Kernel 0: W fp32 [E][H] -> Wt bf16 [H][E], x3. R19: LDS tile transpose.
// Grid (16, 3) x 256 thr; block = 64 e x 64 h tile of one matrix.
// Load: 4 passes x (16 rows x 16 float4) — fully coalesced 256B/row.
// Store: thread t -> row h=t>>2, 16 e's at (t&3)*16 — 2 x uint4 = 32B
// contiguous per thread, 128B per 4-thread group. Pad-68 LDS (~2-way).
// ---------------------------------------------------------------------------
__global__ __launch_bounds__(256) void prep_w2(
    const float* __restrict__ Wq, const float* __restrict__ Wk,
    const float* __restrict__ Wv, unsigned short* __restrict__ Wt)
{
    __shared__ unsigned short L[64][68];   // 8.5 KB, pad-68

    const float* W = blockIdx.y == 0 ? Wq : (blockIdx.y == 1 ? Wk : Wv);
    unsigned short* D = Wt + (size_t)blockIdx.y * (Ec * Hc);
    const int t  = threadIdx.x;
    const int e0 = blockIdx.x * 64;

    // load + convert + transpose into LDS
    const int el_base = t >> 4;          // 0..15
    const int h4      = (t & 15) * 4;    // 0,4,..,60
    #pragma unroll
    for (int p = 0; p < 4; ++p) {
        const int el = p * 16 + el_base;             // 0..63
        const float4 f = *(const float4*)(W + (size_t)(e0 + el) * Hc + h4);
        L[h4 + 0][el] = f2bf(f.x);
        L[h4 + 1][el] = f2bf(f.y);
        L[h4 + 2][el] = f2bf(f.z);
        L[h4 + 3][el] = f2bf(f.w);
    }
    __syncthreads();

    // coalesced row store: 32B/thread
    const int h  = t >> 2;               // 0..63
    const int c0 = (t & 3) * 16;         // 0,16,32,48
    uint4 v0 = *(const uint4*)&L[h][c0];
    uint4 v1 = *(const uint4*)&L[h][c0 + 8];
    *(uint4*)(D + (size_t)h * Ec + e0 + c0)     = v0;
    *(uint4*)(D + (size_t)h * Ec + e0 + c0 + 8) = v1;
}

// ---------------------------------------------------------------------------
// Kernel 1: FUSED QKV projection, MFMA 16x16x32 bf16, K=128 steps, 2-phase
// double-buffer. R17-verbatim (106.15-proven).
// Grid 256 x 512 thr (1 block/CU, 8 waves = 2/SIMD).
// LDS: Xs[2][32][136] (17 KB) + Ws[2][3][64][128] (96 KB) = 113 KB.
// Per K-step: issue next tile (2 float4 X-loads + 6 W-DMA) -> compute cur ->
// convert+ds_write X(next) -> s_waitcnt vmcnt(0) lgkmcnt(0) -> s_barrier.
// W involution (R16-proven): store-side source chunk ^= (row&7); read-side
// colb ^= ((l16&7)<<4).
// ---------------------------------------------------------------------------
__global__ __launch_bounds__(512, 2) void qkv_mfma11(
    const float* __restrict__ X, const unsigned short* __restrict__ Wt,
    unsigned short* __restrict__ Q, unsigned short* __restrict__ K,
    unsigned short* __restrict__ Vt)
{
    __shared__ __align__(16) unsigned short Xs[2][32][136];      // 17.0 KB
    __shared__ __align__(16) unsigned short Ws[2][3][64][128];   // 96.0 KB

    const int tid  = threadIdx.x;
    const int wv   = tid >> 6;          // 0..7
    const int lane = tid & 63;
    const int quad = lane >> 4;
    const int l16  = lane & 15;
    const int rowh = wv >> 2;           // 0..1
    const int wq   = wv & 3;            // 0..3
    const size_t row0 = (size_t)blockIdx.x * 32;

    floatx4 acc[3];
    #pragma unroll
    for (int j = 0; j < 3; ++j)
        #pragma unroll
        for (int r = 0; r < 4; ++r) acc[j][r] = 0.f;

    const int xrow = tid >> 4;         // 0..31
    const int xc4  = (tid & 15) * 4;   // 0,4,..,60

    // ---- prologue: stage buffer 0 (k0 = 0) ----
    {
        float4 xr[2];
        #pragma unroll
        for (int h = 0; h < 2; ++h)
            xr[h] = *(const float4*)(X + (row0 + xrow) * Ec + h * 64 + xc4);
        #pragma unroll
        for (int j = 0; j < 6; ++j) {
            const int flat  = tid + 512 * j;        // 0..3071
            const int which = flat >> 10;
            const int r     = (flat >> 4) & 63;
            const int chunk = (flat & 15) ^ (r & 7);
            const unsigned short* src = Wt + which * 65536 + r * 1024 + chunk * 8;
            char* dst = (char*)&Ws[0][0][0][0] + (wv * 64 + 512 * j) * 16;
            __builtin_amdgcn_global_load_lds(
                (const __attribute__((address_space(1))) unsigned int*)src,
                (__attribute__((address_space(3))) unsigned int*)dst,
                16, 0, 0);
        }
        #pragma unroll
        for (int h = 0; h < 2; ++h) {
            uint2 p;
            p.x = (unsigned int)f2bf(xr[h].x) | ((unsigned int)f2bf(xr[h].y) << 16);
            p.y = (unsigned int)f2bf(xr[h].z) | ((unsigned int)f2bf(xr[h].w) << 16);
            *(uint2*)&Xs[0][xrow][h * 64 + xc4] = p;
        }
        asm volatile("s_waitcnt vmcnt(0) lgkmcnt(0)" ::: "memory");
        __builtin_amdgcn_s_barrier();
    }

    for (int t = 0; t < 8; ++t) {
        const int cur = t & 1;
        float4 xr[2];
        // ---- issue next tile's loads (fly across the compute phase) ----
        if (t < 7) {
            const int k1 = (t + 1) * 128;
            #pragma unroll
            for (int h = 0; h < 2; ++h)
                xr[h] = *(const float4*)(X + (row0 + xrow) * Ec + k1 + h * 64 + xc4);
            #pragma unroll
            for (int j = 0; j < 6; ++j) {
                const int flat  = tid + 512 * j;
                const int which = flat >> 10;
                const int r     = (flat >> 4) & 63;
                const int chunk = (flat & 15) ^ (r & 7);
                const unsigned short* src = Wt + which * 65536 + r * 1024 + k1 + chunk * 8;
                char* dst = (char*)&Ws[cur ^ 1][0][0][0] + (wv * 64 + 512 * j) * 16;
                __builtin_amdgcn_global_load_lds(
                    (const __attribute__((address_space(1))) unsigned int*)src,
                    (__attribute__((address_space(3))) unsigned int*)dst,
                    16, 0, 0);
            }
        }
        __builtin_amdgcn_sched_barrier(0);   // pin load-issue above compute
        // ---- compute on buffer cur ----
        #pragma unroll
        for (int ks = 0; ks < 4; ++ks) {
            const short8 a = *(const short8*)&Xs[cur][rowh * 16 + l16][ks * 32 + quad * 8];
            short8 b[3];
            #pragma unroll
            for (int j = 0; j < 3; ++j) {
                const int f    = 3 * wq + j;
                const int row  = 16 * (f & 3) + l16;
                const int colb = (ks * 64 + quad * 16) ^ ((l16 & 7) << 4);
                b[j] = *(const short8*)((const char*)&Ws[cur][f >> 2][row][0] + colb);
            }
            #pragma unroll
            for (int j = 0; j < 3; ++j)
                acc[j] = __builtin_amdgcn_mfma_f32_16x16x32_bf16(a, b[j], acc[j], 0, 0, 0);
        }
        if (t < 7) {
            __builtin_amdgcn_sched_barrier(0);   // keep X-converts after compute
            // ---- convert + write X(next); X loads had the compute to land ----
            #pragma unroll
            for (int h = 0; h < 2; ++h) {
                uint2 p;
                p.x = (unsigned int)f2bf(xr[h].x) | ((unsigned int)f2bf(xr[h].y) << 16);
                p.y = (unsigned int)f2bf(xr[h].z) | ((unsigned int)f2bf(xr[h].w) << 16);
                *(uint2*)&Xs[cur ^ 1][xrow][h * 64 + xc4] = p;
            }
            asm volatile("s_waitcnt vmcnt(0) lgkmcnt(0)" ::: "memory");
            __builtin_amdgcn_s_barrier();
        }
    }

    // Epilogue. C/D: col = lane&15, row = quad*4 + reg (r7-r12-proven).
    const size_t rbase = row0 + rowh * 16;
    #pragma unroll
    for (int j = 0; j < 3; ++j) {
        const int f  = 3 * wq + j;
        const int mf = f >> 2, nf = f & 3;
        if (mf < 2) {
            unsigned short* O = mf == 0 ? Q : K;
            #pragma unroll
            for (int r = 0; r < 4; ++r) {
                float x = acc[j][r];
                if (!(x > -1.0e4f && x < 1.0e4f)) x = 11111.0f;   // diag
                O[(rbase + quad * 4 + r) * Hc + 16 * nf + l16] = f2bf(x);
            }
        } else {
            // V^T: Vt[b][h][t] (r8-proven). 16-row half shares one b.
            const size_t b  = rbase >> 11;
            const int    t0 = (int)(rbase & 2047) + quad * 4;
            unsigned short* VtB = Vt + b * ((size_t)Hc * Tc);
            unsigned int pk[2];
            #pragma unroll
            for (int half = 0; half < 2; ++half) {
                float x0 = acc[j][half * 2 + 0], x1 = acc[j][half * 2 + 1];
                if (!(x0 > -1.0e4f && x0 < 1.0e4f)) x0 = 11111.0f;
                if (!(x1 > -1.0e4f && x1 < 1.0e4f)) x1 = 11111.0f;
                pk[half] = (unsigned int)f2bf(x0) | ((unsigned int)f2bf(x1) << 16);
            }
            uint2 st; st.x = pk[0]; st.y = pk[1];
            *(uint2*)(VtB + (size_t)(16 * nf + l16) * Tc + t0) = st;
        }
    }
}

// ---------------------------------------------------------------------------
// Kernel 2: causal flash attention — r10/r11/r12-proven core + R15-verified
// polish. R17-verbatim:
//  * balanced dispatch: per-CU (heavy, light) pair sums to 129 k-tiles.
//  * lS pre-reduced across l16 via 4x shfl_xor.
//  * accS epilogue reads as float2.
//  * s_setprio(1) around MFMA clusters.
// ---------------------------------------------------------------------------
__global__ __launch_bounds__(512, 4) void attn_mfma6(
    const unsigned short* __restrict__ Q, const unsigned short* __restrict__ K,
    const unsigned short* __restrict__ Vt, float* __restrict__ Out)
{
    __shared__ __align__(16) unsigned short Pb[8][16][72];   // 18 KB
    __shared__ __align__(16) float accS[8][16][64];          // 32 KB
    __shared__ __align__(16) float lSr[8][16];               // 0.5 KB

    const int tid  = threadIdx.x;
    const int wv   = tid >> 6;            // 0..7
    const int lane = tid & 63;
    const int quad = lane >> 4;
    const int l16  = lane & 15;
    // balanced heavy/light pairing over dispatch-linear id
    const int id   = blockIdx.x + 128 * blockIdx.y;   // 0..511, dispatch order
    const int jj   = id & 255;
    const int qt   = (id < 256) ? (127 - (jj >> 2)) : (jj >> 2);
    const int b    = jj & 3;
    const int qend = qt * 16 + 16;
    const size_t base = (size_t)b * Tc * Hc;
    const unsigned short* VtB = Vt + (size_t)b * Hc * Tc;

    short8 aQ[2];
    #pragma unroll
    for (int ks = 0; ks < 2; ++ks)
        aQ[ks] = *(const short8*)(Q + base +
            (size_t)(qt * 16 + l16) * Hc + ks * 32 + quad * 8);

    floatx4 acc[4];
    float l_st[4];
    #pragma unroll
    for (int nh = 0; nh < 4; ++nh)
        #pragma unroll
        for (int r = 0; r < 4; ++r) acc[nh][r] = 0.f;
    #pragma unroll
    for (int r = 0; r < 4; ++r) l_st[r] = 0.f;

    for (int kb = wv * 64; kb < qend; kb += 512) {
        floatx4 s[4];
        #pragma unroll
        for (int ni = 0; ni < 4; ++ni)
            #pragma unroll
            for (int r = 0; r < 4; ++r) s[ni][r] = 0.f;
        #pragma unroll
        for (int ks = 0; ks < 2; ++ks) {
            short8 bk[4];
            #pragma unroll
            for (int ni = 0; ni < 4; ++ni)
                bk[ni] = *(const short8*)(K + base +
                    (size_t)(kb + 16 * ni + l16) * Hc + ks * 32 + quad * 8);
            __builtin_amdgcn_s_setprio(1);
            #pragma unroll
            for (int ni = 0; ni < 4; ++ni)
                s[ni] = __builtin_amdgcn_mfma_f32_16x16x32_bf16(aQ[ks], bk[ni], s[ni], 0, 0, 0);
            __builtin_amdgcn_s_setprio(0);
        }

        #pragma unroll
        for (int r = 0; r < 4; ++r) {
            const int qrow = qt * 16 + quad * 4 + r;
            #pragma unroll
            for (int ni = 0; ni < 4; ++ni) {
                const int kcol = kb + 16 * ni + l16;
                const float p = (kcol > qrow) ? 0.f : __expf(s[ni][r] * SCALE);
                s[ni][r] = p;
                l_st[r] += p;
            }
        }
        #pragma unroll
        for (int ni = 0; ni < 4; ++ni)
            #pragma unroll
            for (int r = 0; r < 4; ++r)
                Pb[wv][quad * 4 + r][16 * ni + l16] = f2bf(s[ni][r]);

        #pragma unroll
        for (int ks = 0; ks < 2; ++ks) {
            const short8 aP = *(const short8*)&Pb[wv][l16][ks * 32 + quad * 8];
            short8 bv[4];
            #pragma unroll
            for (int nh = 0; nh < 4; ++nh)
                bv[nh] = *(const short8*)(VtB +
                    (size_t)(16 * nh + l16) * Tc + kb + ks * 32 + quad * 8);
            __builtin_amdgcn_s_setprio(1);
            #pragma unroll
            for (int nh = 0; nh < 4; ++nh)
                acc[nh] = __builtin_amdgcn_mfma_f32_16x16x32_bf16(aP, bv[nh], acc[nh], 0, 0, 0);
            __builtin_amdgcn_s_setprio(0);
        }
    }

    #pragma unroll
    for (int nh = 0; nh < 4; ++nh)
        #pragma unroll
        for (int r = 0; r < 4; ++r)
            accS[wv][quad * 4 + r][16 * nh + l16] = acc[nh][r];
    // reduce l_st across the 16 lanes of each quad (xor masks 1,2,4,8 stay
    // within the 16-lane group), then one scalar per (wave, q-row)
    #pragma unroll
    for (int r = 0; r < 4; ++r) {
        float v = l_st[r];
        v += __shfl_xor(v, 1);
        v += __shfl_xor(v, 2);
        v += __shfl_xor(v, 4);
        v += __shfl_xor(v, 8);
        l_st[r] = v;
    }
    if (l16 == 0)
        #pragma unroll
        for (int r = 0; r < 4; ++r)
            lSr[wv][quad * 4 + r] = l_st[r];
    __syncthreads();

    {
        const int q  = tid >> 5;              // 0..15
        const int h0 = (tid & 31) * 2;        // 0..62
        float denom = 0.f;
        #pragma unroll
        for (int w = 0; w < 8; ++w)
            denom += lSr[w][q];
        const float inv = 1.f / denom;
        float o0 = 0.f, o1 = 0.f;
        #pragma unroll
        for (int w = 0; w < 8; ++w) {
            const float2 v = *(const float2*)&accS[w][q][h0];
            o0 += v.x; o1 += v.y;
        }
        o0 *= inv; o1 *= inv;
        if (!(o0 > -1.0e5f && o0 < 1.0e5f)) o0 = 555.0f;   // diag
        if (!(o1 > -1.0e5f && o1 < 1.0e5f)) o1 = 555.0f;
        float2 st; st.x = o0; st.y = o1;
        *(float2*)(Out + base + (size_t)(qt * 16 + q) * Hc + h0) = st;
    }
}

extern "C" void kernel_launch(void* const* d_in, const int* in_sizes, int n_in,
                              void* d_out, int out_size, void* d_ws, size_t ws_size,
                              hipStream_t stream)
{
    const float* X  = (const float*)d_in[0];
    const float* Wq = (const float*)d_in[1];
    const float* Wk = (const float*)d_in[2];
    const float* Wv = (const float*)d_in[3];

    const size_t N = (size_t)Bc * Tc * Hc;          // 524,288
    unsigned short* Wt  = (unsigned short*)d_ws;    // 384 KB bf16 W^T x3
    unsigned short* Qws = Wt + 3 * (size_t)Ec * Hc; // 1 MB
    unsigned short* Kws = Qws + N;                  // 1 MB
    unsigned short* Vtw = Kws + N;                  // 1 MB (V^T [b][h][t])

    prep_w2<<<dim3(16, 3), dim3(256), 0, stream>>>(Wq, Wk, Wv, Wt);
    qkv_mfma11<<<dim3(256), dim3(512), 0, stream>>>(X, Wt, Qws, Kws, Vtw);
    attn_mfma6<<<dim3(128, 4), dim3(512), 0, stream>>>(
        Qws, Kws, Vtw, (float*)d_out);
}